// Round 5
// baseline (143.347 us; speedup 1.0000x reference)
//
#include <hip/hip_runtime.h>

#define GD 128
#define GD3 (GD*GD*GD)
#define KP 27
#define CPB 2048              // cells per block in count/compact
#define NSCAN (GD3 / CPB)     // 1024 scan blocks

typedef __attribute__((ext_vector_type(8))) __bf16 bf16x8;
typedef __attribute__((ext_vector_type(4))) float f32x4;
typedef __attribute__((ext_vector_type(4))) unsigned int u32x4;

__device__ __forceinline__ unsigned short f2bf(float x) {
  unsigned int u = __builtin_bit_cast(unsigned int, x);
  unsigned int r = (u + 0x7FFFu + ((u >> 16) & 1u)) >> 16;  // RNE
  return (unsigned short)r;
}

// Bijective XCD-chunked block swizzle (m204): contiguous work chunk per XCD.
__device__ __forceinline__ int xcd_swz(int bid, int nwg) {
  int q = nwg >> 3, r = nwg & 7;
  int x = bid & 7, inner = bid >> 3;
  int base = (x < r) ? x * (q + 1) : r * (q + 1) + (x - r) * q;
  return base + inner;
}

__global__ void k_init_grid(int* __restrict__ g) {
  int i = (blockIdx.x * 256 + threadIdx.x) * 4;
  if (i < GD3) *(u32x4*)(g + i) = (u32x4){0xFFFFFFFFu,0xFFFFFFFFu,0xFFFFFFFFu,0xFFFFFFFFu};
}

__global__ void k_scatter(const int* __restrict__ coords, int* __restrict__ g, int n) {
  int i = blockIdx.x * 256 + threadIdx.x;
  if (i >= n) return;
  int x = coords[3*i], y = coords[3*i+1], z = coords[3*i+2];
  g[(x << 14) | (y << 7) | z] = i;
}

// Per-block occupied-cell counts (2048 cells/block).
__global__ void k_count(const int* __restrict__ g, int* __restrict__ bcnt) {
  __shared__ int wtot[4];
  int t = threadIdx.x, lane = t & 63, w = t >> 6;
  const int* c = g + blockIdx.x * CPB + t * 8;
  int cnt = 0;
  #pragma unroll
  for (int j = 0; j < 8; j++) cnt += (c[j] >= 0) ? 1 : 0;
  #pragma unroll
  for (int d = 1; d < 64; d <<= 1) cnt += __shfl_xor(cnt, d);
  if (lane == 0) wtot[w] = cnt;
  __syncthreads();
  if (t == 0) bcnt[blockIdx.x] = wtot[0] + wtot[1] + wtot[2] + wtot[3];
}

// Exclusive scan of the 1024 block counts (single block, 1024 threads).
__global__ void k_scan(const int* __restrict__ bcnt, int* __restrict__ boff) {
  __shared__ int s[NSCAN];
  int t = threadIdx.x;
  int v = bcnt[t];
  s[t] = v;
  __syncthreads();
  #pragma unroll
  for (int d = 1; d < NSCAN; d <<= 1) {
    int y = (t >= d) ? s[t - d] : 0;
    __syncthreads();
    s[t] += y;
    __syncthreads();
  }
  boff[t] = s[t] - v;
}

// Compact: rank grid (cell -> sorted idx, -1 if empty), sorted_of, sorted lin, sorted feats.
__global__ void k_compact(const int* __restrict__ g, const float* __restrict__ feats,
                          const int* __restrict__ boff, int* __restrict__ g2,
                          int* __restrict__ sof, int* __restrict__ slin,
                          float* __restrict__ featss) {
  __shared__ int wtot[4];
  int t = threadIdx.x, lane = t & 63, w = t >> 6;
  int cbase = blockIdx.x * CPB + t * 8;
  int v[8]; int cnt = 0;
  #pragma unroll
  for (int j = 0; j < 8; j++) { v[j] = g[cbase + j]; cnt += (v[j] >= 0) ? 1 : 0; }
  int x = cnt;
  #pragma unroll
  for (int d = 1; d < 64; d <<= 1) { int y = __shfl_up(x, d); if (lane >= d) x += y; }
  if (lane == 63) wtot[w] = x;
  __syncthreads();
  int wbase = 0;
  for (int ww = 0; ww < w; ww++) wbase += wtot[ww];
  int pos = boff[blockIdx.x] + wbase + (x - cnt);
  #pragma unroll
  for (int j = 0; j < 8; j++) {
    int o = v[j];
    if (o >= 0) {
      g2[cbase + j] = pos;
      sof[pos] = o;
      slin[pos] = cbase + j;
      featss[pos] = feats[o];
      pos++;
    } else {
      g2[cbase + j] = -1;
    }
  }
}

// Pack w2 (27,16,32) and w3 (27,32,64) into MFMA B-fragment order, bf16.
// wpk[k][chunk][lane][j] = W[k][ci][co], ci=(lane>>4)*8+j, co=chunk*16+(lane&15).
// Leftover threads zero row n of x1bf (16ch) / x2bf (32ch).
__global__ void k_wpack(const float* __restrict__ w2, const float* __restrict__ w3,
                        unsigned short* __restrict__ w2pk, unsigned short* __restrict__ w3pk,
                        unsigned short* __restrict__ x1bf, unsigned short* __restrict__ x2bf,
                        int n) {
  int gid = blockIdx.x * 256 + threadIdx.x;
  const int N2 = KP * 2 * 64;
  const int N3 = KP * 4 * 64;
  if (gid < N2) {
    int k = gid >> 7, rem = gid & 127, c = rem >> 6, l = rem & 63;
    int gq = l >> 4, col = l & 15;
    #pragma unroll
    for (int j = 0; j < 8; j++) {
      int ci = gq * 8 + j, co = c * 16 + col;
      float v = (ci < 16) ? w2[(k * 16 + ci) * 32 + co] : 0.f;
      w2pk[gid * 8 + j] = f2bf(v);
    }
  } else if (gid < N2 + N3) {
    int g2 = gid - N2;
    int k = g2 >> 8, rem = g2 & 255, c = rem >> 6, l = rem & 63;
    int gq = l >> 4, col = l & 15;
    #pragma unroll
    for (int j = 0; j < 8; j++) {
      int ci = gq * 8 + j, co = c * 16 + col;
      float v = w3[(k * 32 + ci) * 64 + co];
      w3pk[g2 * 8 + j] = f2bf(v);
    }
  } else if (gid == N2 + N3) {
    u32x4 z = {0u,0u,0u,0u};
    u32x4* d = (u32x4*)(x1bf + (size_t)n * 16);
    d[0] = z; d[1] = z;
  } else if (gid == N2 + N3 + 1) {
    u32x4 z = {0u,0u,0u,0u};
    u32x4* d = (u32x4*)(x2bf + (size_t)n * 32);
    d[0] = z; d[1] = z; d[2] = z; d[3] = z;
  }
}

// Rulebook build in SORTED space, fused with conv1 (1->16 ch).
// nbr layout (per 32-row group g, pair-packed for int2 loads):
//   nbr[k*npad + g*32 + col*2 + t] = index for sorted row g*32 + t*16 + col (n if inactive).
// x1 rows are 16 channels (32 B).
__global__ void k_nbr_conv1(const int* __restrict__ slin, const float* __restrict__ featss,
                            const float* __restrict__ w1, const int* __restrict__ g2,
                            int* __restrict__ nbr, unsigned short* __restrict__ x1bf,
                            int n, int npad) {
  int bid = xcd_swz(blockIdx.x, gridDim.x);
  int i = bid * 256 + threadIdx.x;
  if (i >= npad) return;
  const int slot = (i & ~31) * 1 + ((i & 15) << 1) + ((i >> 4) & 1);  // pair-packed position
  if (i >= n) {
    #pragma unroll
    for (int k = 0; k < KP; k++) nbr[k*npad + slot] = n;
    return;
  }
  int lin = slin[i];
  int x = lin >> 14, y = (lin >> 7) & 127, z = lin & 127;
  float acc[16];
  #pragma unroll
  for (int c = 0; c < 16; c++) acc[c] = 0.f;
  #pragma unroll
  for (int k = 0; k < 27; k++) {
    const int dx = k/9 - 1, dy = (k/3)%3 - 1, dz = k%3 - 1;
    int nx = x+dx, ny = y+dy, nz = z+dz;
    int idx = -1;
    if (((unsigned)nx < 128u) && ((unsigned)ny < 128u) && ((unsigned)nz < 128u))
      idx = g2[(nx << 14) | (ny << 7) | nz];
    nbr[k*npad + slot] = (idx >= 0) ? idx : n;
    float f = 0.f;
    if (idx >= 0) f = featss[idx];
    #pragma unroll
    for (int c = 0; c < 16; c++) acc[c] = fmaf(f, w1[k*16+c], acc[c]);
  }
  u32x4 d0, d1;
  d0.x = (unsigned)f2bf(acc[0])  | ((unsigned)f2bf(acc[1])  << 16);
  d0.y = (unsigned)f2bf(acc[2])  | ((unsigned)f2bf(acc[3])  << 16);
  d0.z = (unsigned)f2bf(acc[4])  | ((unsigned)f2bf(acc[5])  << 16);
  d0.w = (unsigned)f2bf(acc[6])  | ((unsigned)f2bf(acc[7])  << 16);
  d1.x = (unsigned)f2bf(acc[8])  | ((unsigned)f2bf(acc[9])  << 16);
  d1.y = (unsigned)f2bf(acc[10]) | ((unsigned)f2bf(acc[11]) << 16);
  d1.z = (unsigned)f2bf(acc[12]) | ((unsigned)f2bf(acc[13]) << 16);
  d1.w = (unsigned)f2bf(acc[14]) | ((unsigned)f2bf(acc[15]) << 16);
  u32x4* dst = (u32x4*)(x1bf + (size_t)i * 16);
  dst[0] = d0; dst[1] = d1;
}

// Gather-MFMA conv layer, two-phase: (1) preload ALL 27x2 neighbor indices into
// registers (int2, no downstream dependency), (2) unrolled gather+MFMA stream.
// XSTRIDE = shorts per xin row (16 for conv2: upper 16 ch structurally zero; 32 for conv3).
template<int CHUNKS, int XSTRIDE>
__launch_bounds__(256, 3)
__global__ void k_conv(const int* __restrict__ nbr, const unsigned short* __restrict__ xin,
                       const unsigned short* __restrict__ wpk, unsigned short* __restrict__ xout,
                       const float* __restrict__ wm, const float* __restrict__ bm,
                       float* __restrict__ outf, const int* __restrict__ sof,
                       int n, int npad) {
  const int lane = threadIdx.x & 63;
  const int bid = xcd_swz(blockIdx.x, gridDim.x);
  const int wid = bid * 4 + (threadIdx.x >> 6);
  const int base = wid * 32;
  if (base >= npad) return;
  const int col = lane & 15, grp = lane >> 4;

  // Phase 1: all neighbor indices, pair-packed -> one dwordx2 per k.
  int2 idx[KP];
  #pragma unroll
  for (int k = 0; k < KP; k++)
    idx[k] = *(const int2*)(nbr + (size_t)k * npad + base + col * 2);

  f32x4 acc[2][CHUNKS];
  #pragma unroll
  for (int t = 0; t < 2; t++)
    #pragma unroll
    for (int c = 0; c < CHUNKS; c++) acc[t][c] = (f32x4){0.f,0.f,0.f,0.f};
  const bf16x8 az = __builtin_bit_cast(bf16x8, (u32x4){0u,0u,0u,0u});

  // Phase 2: gather + B-load + MFMA, no index dependency.
  #pragma unroll
  for (int k = 0; k < KP; ++k) {
    bf16x8 a0 = az, a1 = az;
    if (XSTRIDE == 32 || grp < 2) {
      a0 = *(const bf16x8*)(xin + (size_t)idx[k].x * XSTRIDE + grp * 8);
      a1 = *(const bf16x8*)(xin + (size_t)idx[k].y * XSTRIDE + grp * 8);
    }
    bf16x8 b[CHUNKS];
    #pragma unroll
    for (int c = 0; c < CHUNKS; c++)
      b[c] = *(const bf16x8*)(wpk + ((size_t)((k * CHUNKS + c) * 64 + lane)) * 8);
    #pragma unroll
    for (int c = 0; c < CHUNKS; c++) {
      acc[0][c] = __builtin_amdgcn_mfma_f32_16x16x32_bf16(a0, b[c], acc[0][c], 0, 0, 0);
      acc[1][c] = __builtin_amdgcn_mfma_f32_16x16x32_bf16(a1, b[c], acc[1][c], 0, 0, 0);
    }
  }

  if constexpr (CHUNKS == 2) {
    #pragma unroll
    for (int t = 0; t < 2; t++)
      #pragma unroll
      for (int c = 0; c < CHUNKS; c++)
        #pragma unroll
        for (int r = 0; r < 4; r++) {
          int m = base + t*16 + grp*4 + r;
          if (m < n) xout[(size_t)m * 32 + c*16 + col] = f2bf(acc[t][c][r]);
        }
  } else {
    float wmv[CHUNKS][3];
    #pragma unroll
    for (int c = 0; c < CHUNKS; c++)
      #pragma unroll
      for (int j = 0; j < 3; j++) wmv[c][j] = wm[(c*16 + col)*3 + j];
    float bb0 = bm[0], bb1 = bm[1], bb2 = bm[2];
    #pragma unroll
    for (int t = 0; t < 2; t++)
      #pragma unroll
      for (int r = 0; r < 4; r++) {
        float p0 = 0.f, p1 = 0.f, p2 = 0.f;
        #pragma unroll
        for (int c = 0; c < CHUNKS; c++) {
          float v = acc[t][c][r];
          p0 = fmaf(v, wmv[c][0], p0);
          p1 = fmaf(v, wmv[c][1], p1);
          p2 = fmaf(v, wmv[c][2], p2);
        }
        #pragma unroll
        for (int msk = 1; msk <= 8; msk <<= 1) {
          p0 += __shfl_xor(p0, msk);
          p1 += __shfl_xor(p1, msk);
          p2 += __shfl_xor(p2, msk);
        }
        if (col == 0) {
          int m = base + t*16 + grp*4 + r;
          if (m < n) {
            int o = sof[m];
            outf[o*3+0] = p0 + bb0;
            outf[o*3+1] = p1 + bb1;
            outf[o*3+2] = p2 + bb2;
          }
        }
      }
  }
}

extern "C" void kernel_launch(void* const* d_in, const int* in_sizes, int n_in,
                              void* d_out, int out_size, void* d_ws, size_t ws_size,
                              hipStream_t stream) {
  (void)n_in; (void)out_size; (void)ws_size;
  const int*   coords = (const int*)d_in[0];
  const float* feats  = (const float*)d_in[1];
  const float* w1     = (const float*)d_in[2];
  const float* w2     = (const float*)d_in[3];
  const float* w3     = (const float*)d_in[4];
  const float* wm     = (const float*)d_in[5];
  const float* bm     = (const float*)d_in[6];
  float* outf = (float*)d_out;
  const int n = in_sizes[0] / 3;
  const int npad = (n + 31) & ~31;

  char* ws = (char*)d_ws;
  size_t off = 0;
  int* grid = (int*)(ws + off); off += (size_t)GD3 * 4;
  int* g2   = (int*)(ws + off); off += (size_t)GD3 * 4;
  int* nbr  = (int*)(ws + off); off += (size_t)KP * npad * 4;
  off = (off + 255) & ~(size_t)255;
  int* bcnt = (int*)(ws + off); off += (size_t)NSCAN * 4;
  int* boff = (int*)(ws + off); off += (size_t)NSCAN * 4;
  off = (off + 255) & ~(size_t)255;
  int* sof  = (int*)(ws + off); off += (size_t)npad * 4;
  int* slin = (int*)(ws + off); off += (size_t)npad * 4;
  float* featss = (float*)(ws + off); off += (size_t)npad * 4;
  off = (off + 255) & ~(size_t)255;
  unsigned short* x1bf = (unsigned short*)(ws + off); off += ((size_t)n + 1) * 16 * 2;
  off = (off + 255) & ~(size_t)255;
  unsigned short* x2bf = (unsigned short*)(ws + off); off += ((size_t)n + 1) * 32 * 2;
  off = (off + 255) & ~(size_t)255;
  unsigned short* w2pk = (unsigned short*)(ws + off); off += (size_t)KP * 2 * 64 * 8 * 2;
  off = (off + 255) & ~(size_t)255;
  unsigned short* w3pk = (unsigned short*)(ws + off); off += (size_t)KP * 4 * 64 * 8 * 2;

  hipLaunchKernelGGL(k_init_grid, dim3(GD3 / 1024), dim3(256), 0, stream, grid);
  hipLaunchKernelGGL(k_scatter, dim3((n + 255) / 256), dim3(256), 0, stream, coords, grid, n);
  hipLaunchKernelGGL(k_count, dim3(NSCAN), dim3(256), 0, stream, grid, bcnt);
  hipLaunchKernelGGL(k_scan, dim3(1), dim3(NSCAN), 0, stream, bcnt, boff);
  hipLaunchKernelGGL(k_compact, dim3(NSCAN), dim3(256), 0, stream,
                     grid, feats, boff, g2, sof, slin, featss);
  {
    const int items = KP * 2 * 64 + KP * 4 * 64 + 2;
    hipLaunchKernelGGL(k_wpack, dim3((items + 255) / 256), dim3(256), 0, stream,
                       w2, w3, w2pk, w3pk, x1bf, x2bf, n);
  }
  hipLaunchKernelGGL(k_nbr_conv1, dim3((npad + 255) / 256), dim3(256), 0, stream,
                     slin, featss, w1, g2, nbr, x1bf, n, npad);
  const int waves = npad / 32;
  const int cblocks = (waves + 3) / 4;
  hipLaunchKernelGGL((k_conv<2,16>), dim3(cblocks), dim3(256), 0, stream,
                     nbr, x1bf, w2pk, x2bf, nullptr, nullptr, nullptr, nullptr, n, npad);
  hipLaunchKernelGGL((k_conv<4,32>), dim3(cblocks), dim3(256), 0, stream,
                     nbr, x2bf, w3pk, nullptr, wm, bm, outf, sof, n, npad);
}

// Round 8
// 117.839 us; speedup vs baseline: 1.2165x; 1.2165x over previous
//
#include <hip/hip_runtime.h>

#define GD 128
#define GD3 (GD*GD*GD)
#define NPL 36               // nbr planes: 27 real + pads (filled with n)
#define CPB 2048
#define NSCAN (GD3 / CPB)

typedef __attribute__((ext_vector_type(8))) __bf16 bf16x8;
typedef __attribute__((ext_vector_type(4))) float f32x4;
typedef __attribute__((ext_vector_type(4))) unsigned int u32x4;

#define SB() __builtin_amdgcn_sched_barrier(0)

__device__ __forceinline__ unsigned short f2bf(float x) {
  unsigned int u = __builtin_bit_cast(unsigned int, x);
  unsigned int r = (u + 0x7FFFu + ((u >> 16) & 1u)) >> 16;  // RNE
  return (unsigned short)r;
}

// Bijective XCD-chunked block swizzle (m204).
__device__ __forceinline__ int xcd_swz(int bid, int nwg) {
  int q = nwg >> 3, r = nwg & 7;
  int x = bid & 7, inner = bid >> 3;
  int base = (x < r) ? x * (q + 1) : r * (q + 1) + (x - r) * q;
  return base + inner;
}

__global__ void k_init_grid(int* __restrict__ g) {
  int i = (blockIdx.x * 256 + threadIdx.x) * 4;
  if (i < GD3) *(u32x4*)(g + i) = (u32x4){0xFFFFFFFFu,0xFFFFFFFFu,0xFFFFFFFFu,0xFFFFFFFFu};
}

__global__ void k_scatter(const int* __restrict__ coords, int* __restrict__ g, int n) {
  int i = blockIdx.x * 256 + threadIdx.x;
  if (i >= n) return;
  int x = coords[3*i], y = coords[3*i+1], z = coords[3*i+2];
  g[(x << 14) | (y << 7) | z] = i;
}

__global__ void k_count(const int* __restrict__ g, int* __restrict__ bcnt) {
  __shared__ int wtot[4];
  int t = threadIdx.x, lane = t & 63, w = t >> 6;
  const int* c = g + blockIdx.x * CPB + t * 8;
  int cnt = 0;
  #pragma unroll
  for (int j = 0; j < 8; j++) cnt += (c[j] >= 0) ? 1 : 0;
  #pragma unroll
  for (int d = 1; d < 64; d <<= 1) cnt += __shfl_xor(cnt, d);
  if (lane == 0) wtot[w] = cnt;
  __syncthreads();
  if (t == 0) bcnt[blockIdx.x] = wtot[0] + wtot[1] + wtot[2] + wtot[3];
}

__global__ void k_scan(const int* __restrict__ bcnt, int* __restrict__ boff) {
  __shared__ int s[NSCAN];
  int t = threadIdx.x;
  int v = bcnt[t];
  s[t] = v;
  __syncthreads();
  #pragma unroll
  for (int d = 1; d < NSCAN; d <<= 1) {
    int y = (t >= d) ? s[t - d] : 0;
    __syncthreads();
    s[t] += y;
    __syncthreads();
  }
  boff[t] = s[t] - v;
}

// Compact in-place: grid cell -> sorted rank (-1 if empty); emit sof/slin/featss.
__global__ void k_compact(int* __restrict__ g, const float* __restrict__ feats,
                          const int* __restrict__ boff,
                          int* __restrict__ sof, int* __restrict__ slin,
                          float* __restrict__ featss) {
  __shared__ int wtot[4];
  int t = threadIdx.x, lane = t & 63, w = t >> 6;
  int cbase = blockIdx.x * CPB + t * 8;
  int v[8]; int cnt = 0;
  #pragma unroll
  for (int j = 0; j < 8; j++) { v[j] = g[cbase + j]; cnt += (v[j] >= 0) ? 1 : 0; }
  int x = cnt;
  #pragma unroll
  for (int d = 1; d < 64; d <<= 1) { int y = __shfl_up(x, d); if (lane >= d) x += y; }
  if (lane == 63) wtot[w] = x;
  __syncthreads();
  int wbase = 0;
  for (int ww = 0; ww < w; ww++) wbase += wtot[ww];
  int pos = boff[blockIdx.x] + wbase + (x - cnt);
  #pragma unroll
  for (int j = 0; j < 8; j++) {
    int o = v[j];
    if (o >= 0) {
      g[cbase + j] = pos;
      sof[pos] = o;
      slin[pos] = cbase + j;
      featss[pos] = feats[o];
      pos++;
    } else {
      g[cbase + j] = -1;
    }
  }
}

// Pack weights into MFMA B-fragment order, bf16.
// w3pk: 29 planes [k][c:4][lane][8], zero for k>=27. value = w3[k][ci][co],
//   ci=(lane>>4)*8+j, co=c*16+(lane&15).
// w2pk PAIRED: 16 steps [s][c:2][lane][8]; k=2s+(gq>>1), ci=(gq&1)*8+j (gq=lane>>4),
//   co=c*16+col; zero for k>=27.
// Leftover threads zero row n of x1bf (16ch) / x2bf (32ch).
__global__ void k_wpack(const float* __restrict__ w2, const float* __restrict__ w3,
                        unsigned short* __restrict__ w2pk, unsigned short* __restrict__ w3pk,
                        unsigned short* __restrict__ x1bf, unsigned short* __restrict__ x2bf,
                        int n) {
  int gid = blockIdx.x * 256 + threadIdx.x;
  const int N3 = 29 * 4 * 64;   // 7424
  const int N2 = 16 * 2 * 64;   // 2048
  if (gid < N3) {
    int k = gid >> 8, rem = gid & 255, c = rem >> 6, l = rem & 63;
    int gq = l >> 4, col = l & 15;
    #pragma unroll
    for (int j = 0; j < 8; j++) {
      int ci = gq * 8 + j, co = c * 16 + col;
      float v = (k < 27) ? w3[(k * 32 + ci) * 64 + co] : 0.f;
      w3pk[gid * 8 + j] = f2bf(v);
    }
  } else if (gid < N3 + N2) {
    int g2 = gid - N3;
    int s = g2 >> 7, rem = g2 & 127, c = rem >> 6, l = rem & 63;
    int gq = l >> 4, col = l & 15;
    int k = 2 * s + (gq >> 1);
    #pragma unroll
    for (int j = 0; j < 8; j++) {
      int ci = (gq & 1) * 8 + j, co = c * 16 + col;
      float v = (k < 27) ? w2[(k * 16 + ci) * 32 + co] : 0.f;
      w2pk[g2 * 8 + j] = f2bf(v);
    }
  } else if (gid == N3 + N2) {
    u32x4 z = {0u,0u,0u,0u};
    u32x4* d = (u32x4*)(x1bf + (size_t)n * 16);
    d[0] = z; d[1] = z;
  } else if (gid == N3 + N2 + 1) {
    u32x4 z = {0u,0u,0u,0u};
    u32x4* d = (u32x4*)(x2bf + (size_t)n * 32);
    d[0] = z; d[1] = z; d[2] = z; d[3] = z;
  }
}

// Rulebook (sorted space, pair-packed slots, inactive -> n) fused with conv1.
// Phase-split: 27 branchless grid lookups issued up front -> fence -> nbr writes +
// feature gathers -> fence -> conv1 FMAs. slot: (i&~31) + (i&15)*2 + ((i>>4)&1).
__global__ void k_nbr_conv1(const int* __restrict__ slin, const float* __restrict__ featss,
                            const float* __restrict__ w1, const int* __restrict__ g2,
                            int* __restrict__ nbr, unsigned short* __restrict__ x1bf,
                            int n, int npad) {
  int bid = xcd_swz(blockIdx.x, gridDim.x);
  int i = bid * 256 + threadIdx.x;
  if (i >= npad) return;
  const int slot = (i & ~31) + ((i & 15) << 1) + ((i >> 4) & 1);
  if (i >= n) {
    #pragma unroll
    for (int k = 0; k < NPL; k++) nbr[k*npad + slot] = n;
    return;
  }
  int lin = slin[i];
  int x = lin >> 14, y = (lin >> 7) & 127, z = lin & 127;
  // Phase 1: all 27 grid lookups, branchless, issued together.
  int idxs[27];
  #pragma unroll
  for (int k = 0; k < 27; k++) {
    const int dx = k/9 - 1, dy = (k/3)%3 - 1, dz = k%3 - 1;
    int nx = x+dx, ny = y+dy, nz = z+dz;
    bool valid = ((unsigned)nx < 128u) && ((unsigned)ny < 128u) && ((unsigned)nz < 128u);
    int nlin = valid ? ((nx << 14) | (ny << 7) | nz) : 0;
    int v = g2[nlin];
    idxs[k] = valid ? v : -1;
  }
  SB();
  // Phase 2: rulebook writes + feature gathers.
  float fv[27];
  #pragma unroll
  for (int k = 0; k < 27; k++) {
    int idx = idxs[k];
    nbr[k*npad + slot] = (idx >= 0) ? idx : n;
    float f = featss[(idx >= 0) ? idx : 0];
    fv[k] = (idx >= 0) ? f : 0.f;
  }
  #pragma unroll
  for (int k = 27; k < NPL; k++) nbr[k*npad + slot] = n;
  SB();
  // Phase 3: conv1 (1->16) FMAs.
  float acc[16];
  #pragma unroll
  for (int c = 0; c < 16; c++) acc[c] = 0.f;
  #pragma unroll
  for (int k = 0; k < 27; k++)
    #pragma unroll
    for (int c = 0; c < 16; c++) acc[c] = fmaf(fv[k], w1[k*16+c], acc[c]);
  u32x4 d0, d1;
  d0.x = (unsigned)f2bf(acc[0])  | ((unsigned)f2bf(acc[1])  << 16);
  d0.y = (unsigned)f2bf(acc[2])  | ((unsigned)f2bf(acc[3])  << 16);
  d0.z = (unsigned)f2bf(acc[4])  | ((unsigned)f2bf(acc[5])  << 16);
  d0.w = (unsigned)f2bf(acc[6])  | ((unsigned)f2bf(acc[7])  << 16);
  d1.x = (unsigned)f2bf(acc[8])  | ((unsigned)f2bf(acc[9])  << 16);
  d1.y = (unsigned)f2bf(acc[10]) | ((unsigned)f2bf(acc[11]) << 16);
  d1.z = (unsigned)f2bf(acc[12]) | ((unsigned)f2bf(acc[13]) << 16);
  d1.w = (unsigned)f2bf(acc[14]) | ((unsigned)f2bf(acc[15]) << 16);
  u32x4* dst = (u32x4*)(x1bf + (size_t)i * 16);
  dst[0] = d0; dst[1] = d1;
}

// conv2, k-PAIRED (14 MFMA steps). Register pipeline, sched_barrier phase fences,
// all waitcnts compiler-inserted. ixs fully preloaded; A gathered 3 steps ahead
// (ring %4), B 2 ahead (ring %3).
__launch_bounds__(256, 3)
__global__ void k_conv2r(const int* __restrict__ nbr, const unsigned short* __restrict__ xin,
                         const unsigned short* __restrict__ wpk,
                         unsigned short* __restrict__ xout, int n, int npad) {
  const int lane = threadIdx.x & 63;
  const int w = threadIdx.x >> 6;
  const int bid = xcd_swz(blockIdx.x, gridDim.x);
  const int base = (bid * 4 + w) * 32;
  if (base >= npad) return;
  const int col = lane & 15, grp = lane >> 4;
  const int kg = grp >> 1;                        // pair member (0/1) per lane
  const int* nb = nbr + base + col * 2;           // plane p at + p*npad
  const unsigned short* xg = xin + (grp & 1) * 8; // + idx*16
  const unsigned short* wl = wpk + lane * 8;      // step s chunk c at + (s*2+c)*512

  // Phase 0: all pair-step indices (this lane's plane = 2s+kg).
  int2 ixs[14];
  #pragma unroll
  for (int s = 0; s < 14; s++)
    ixs[s] = *(const int2*)(nb + (size_t)(2*s + kg) * npad);
  SB();
  // Prologue: B steps 0,1; A steps 0,1,2.
  bf16x8 bst[3][2];
  bf16x8 ga[4][2];
  #pragma unroll
  for (int c = 0; c < 2; c++) bst[0][c] = *(const bf16x8*)(wl + (size_t)(0*2+c)*512);
  #pragma unroll
  for (int c = 0; c < 2; c++) bst[1][c] = *(const bf16x8*)(wl + (size_t)(1*2+c)*512);
  #pragma unroll
  for (int s = 0; s < 3; s++) {
    ga[s][0] = *(const bf16x8*)(xg + (size_t)ixs[s].x * 16);
    ga[s][1] = *(const bf16x8*)(xg + (size_t)ixs[s].y * 16);
  }
  SB();

  f32x4 acc[2][2];
  #pragma unroll
  for (int t = 0; t < 2; t++)
    #pragma unroll
    for (int c = 0; c < 2; c++) acc[t][c] = (f32x4){0.f,0.f,0.f,0.f};

  #pragma unroll
  for (int s = 0; s < 14; ++s) {
    SB();
    #pragma unroll
    for (int c = 0; c < 2; c++) {
      acc[0][c] = __builtin_amdgcn_mfma_f32_16x16x32_bf16(ga[s%4][0], bst[s%3][c], acc[0][c], 0, 0, 0);
      acc[1][c] = __builtin_amdgcn_mfma_f32_16x16x32_bf16(ga[s%4][1], bst[s%3][c], acc[1][c], 0, 0, 0);
    }
    SB();
    if (s + 2 < 14) {
      #pragma unroll
      for (int c = 0; c < 2; c++)
        bst[(s+2)%3][c] = *(const bf16x8*)(wl + (size_t)((s+2)*2+c)*512);
    }
    if (s + 3 < 14) {
      ga[(s+3)%4][0] = *(const bf16x8*)(xg + (size_t)ixs[s+3].x * 16);
      ga[(s+3)%4][1] = *(const bf16x8*)(xg + (size_t)ixs[s+3].y * 16);
    }
  }

  #pragma unroll
  for (int t = 0; t < 2; t++)
    #pragma unroll
    for (int c = 0; c < 2; c++)
      #pragma unroll
      for (int r = 0; r < 4; r++) {
        int m = base + t*16 + grp*4 + r;
        if (m < n) xout[(size_t)m * 32 + c*16 + col] = f2bf(acc[t][c][r]);
      }
}

// conv3 (27 planes, 4 chunks) register pipeline + fused 64->3 head.
// ixs ring %5 (load plane k+5), A gathers ring %4 (plane k+3), B ring %3 (plane k+2).
__launch_bounds__(256, 3)
__global__ void k_conv3r(const int* __restrict__ nbr, const unsigned short* __restrict__ xin,
                         const unsigned short* __restrict__ wpk,
                         const float* __restrict__ wm, const float* __restrict__ bm,
                         float* __restrict__ outf, const int* __restrict__ sof,
                         int n, int npad) {
  const int lane = threadIdx.x & 63;
  const int w = threadIdx.x >> 6;
  const int bid = xcd_swz(blockIdx.x, gridDim.x);
  const int base = (bid * 4 + w) * 32;
  if (base >= npad) return;
  const int col = lane & 15, grp = lane >> 4;
  const int* nb = nbr + base + col * 2;
  const unsigned short* xg = xin + grp * 8;      // + idx*32
  const unsigned short* wl = wpk + lane * 8;     // plane k chunk c at + (k*4+c)*512

  int2 ixs[5];
  #pragma unroll
  for (int k = 0; k < 5; k++) ixs[k] = *(const int2*)(nb + (size_t)k * npad);
  SB();
  bf16x8 bst[3][4];
  bf16x8 ga[4][2];
  #pragma unroll
  for (int c = 0; c < 4; c++) bst[0][c] = *(const bf16x8*)(wl + (size_t)(0*4+c)*512);
  #pragma unroll
  for (int c = 0; c < 4; c++) bst[1][c] = *(const bf16x8*)(wl + (size_t)(1*4+c)*512);
  #pragma unroll
  for (int k = 0; k < 3; k++) {
    ga[k][0] = *(const bf16x8*)(xg + (size_t)ixs[k].x * 32);
    ga[k][1] = *(const bf16x8*)(xg + (size_t)ixs[k].y * 32);
  }
  SB();

  f32x4 acc[2][4];
  #pragma unroll
  for (int t = 0; t < 2; t++)
    #pragma unroll
    for (int c = 0; c < 4; c++) acc[t][c] = (f32x4){0.f,0.f,0.f,0.f};

  #pragma unroll
  for (int k = 0; k < 27; ++k) {
    SB();
    #pragma unroll
    for (int c = 0; c < 4; c++) {
      acc[0][c] = __builtin_amdgcn_mfma_f32_16x16x32_bf16(ga[k%4][0], bst[k%3][c], acc[0][c], 0, 0, 0);
      acc[1][c] = __builtin_amdgcn_mfma_f32_16x16x32_bf16(ga[k%4][1], bst[k%3][c], acc[1][c], 0, 0, 0);
    }
    SB();
    ixs[k%5] = *(const int2*)(nb + (size_t)(k + 5) * npad);   // plane k+5 <= 31 < NPL
    #pragma unroll
    for (int c = 0; c < 4; c++)
      bst[(k+2)%3][c] = *(const bf16x8*)(wl + (size_t)((k+2)*4+c)*512);  // <= 28
    int2 g = ixs[(k+3)%5];                                    // plane k+3 (2 iters old)
    ga[(k+3)%4][0] = *(const bf16x8*)(xg + (size_t)g.x * 32); // plane k+3 <= 29
    ga[(k+3)%4][1] = *(const bf16x8*)(xg + (size_t)g.y * 32);
  }

  float wmv[4][3];
  #pragma unroll
  for (int c = 0; c < 4; c++)
    #pragma unroll
    for (int j = 0; j < 3; j++) wmv[c][j] = wm[(c*16 + col)*3 + j];
  float bb0 = bm[0], bb1 = bm[1], bb2 = bm[2];
  #pragma unroll
  for (int t = 0; t < 2; t++)
    #pragma unroll
    for (int r = 0; r < 4; r++) {
      float p0 = 0.f, p1 = 0.f, p2 = 0.f;
      #pragma unroll
      for (int c = 0; c < 4; c++) {
        float v = acc[t][c][r];
        p0 = fmaf(v, wmv[c][0], p0);
        p1 = fmaf(v, wmv[c][1], p1);
        p2 = fmaf(v, wmv[c][2], p2);
      }
      #pragma unroll
      for (int msk = 1; msk <= 8; msk <<= 1) {
        p0 += __shfl_xor(p0, msk);
        p1 += __shfl_xor(p1, msk);
        p2 += __shfl_xor(p2, msk);
      }
      if (col == 0) {
        int m = base + t*16 + grp*4 + r;
        if (m < n) {
          int o = sof[m];
          outf[o*3+0] = p0 + bb0;
          outf[o*3+1] = p1 + bb1;
          outf[o*3+2] = p2 + bb2;
        }
      }
    }
}

extern "C" void kernel_launch(void* const* d_in, const int* in_sizes, int n_in,
                              void* d_out, int out_size, void* d_ws, size_t ws_size,
                              hipStream_t stream) {
  (void)n_in; (void)out_size; (void)ws_size;
  const int*   coords = (const int*)d_in[0];
  const float* feats  = (const float*)d_in[1];
  const float* w1     = (const float*)d_in[2];
  const float* w2     = (const float*)d_in[3];
  const float* w3     = (const float*)d_in[4];
  const float* wm     = (const float*)d_in[5];
  const float* bm     = (const float*)d_in[6];
  float* outf = (float*)d_out;
  const int n = in_sizes[0] / 3;
  const int npad = (n + 31) & ~31;

  char* ws = (char*)d_ws;
  size_t off = 0;
  int* grid = (int*)(ws + off); off += (size_t)GD3 * 4;
  int* nbr  = (int*)(ws + off); off += (size_t)NPL * npad * 4;
  off = (off + 255) & ~(size_t)255;
  int* bcnt = (int*)(ws + off); off += (size_t)NSCAN * 4;
  int* boff = (int*)(ws + off); off += (size_t)NSCAN * 4;
  off = (off + 255) & ~(size_t)255;
  int* sof  = (int*)(ws + off); off += (size_t)npad * 4;
  int* slin = (int*)(ws + off); off += (size_t)npad * 4;
  float* featss = (float*)(ws + off); off += (size_t)npad * 4;
  off = (off + 255) & ~(size_t)255;
  unsigned short* x1bf = (unsigned short*)(ws + off); off += ((size_t)n + 1) * 16 * 2;
  off = (off + 255) & ~(size_t)255;
  unsigned short* x2bf = (unsigned short*)(ws + off); off += ((size_t)n + 1) * 32 * 2;
  off = (off + 255) & ~(size_t)255;
  unsigned short* w2pk = (unsigned short*)(ws + off); off += (size_t)16 * 2 * 64 * 8 * 2;
  off = (off + 255) & ~(size_t)255;
  unsigned short* w3pk = (unsigned short*)(ws + off); off += (size_t)29 * 4 * 64 * 8 * 2;

  hipLaunchKernelGGL(k_init_grid, dim3(GD3 / 1024), dim3(256), 0, stream, grid);
  hipLaunchKernelGGL(k_scatter, dim3((n + 255) / 256), dim3(256), 0, stream, coords, grid, n);
  hipLaunchKernelGGL(k_count, dim3(NSCAN), dim3(256), 0, stream, grid, bcnt);
  hipLaunchKernelGGL(k_scan, dim3(1), dim3(NSCAN), 0, stream, bcnt, boff);
  hipLaunchKernelGGL(k_compact, dim3(NSCAN), dim3(256), 0, stream,
                     grid, feats, boff, sof, slin, featss);
  {
    const int items = 29*4*64 + 16*2*64 + 2;
    hipLaunchKernelGGL(k_wpack, dim3((items + 255) / 256), dim3(256), 0, stream,
                       w2, w3, w2pk, w3pk, x1bf, x2bf, n);
  }
  hipLaunchKernelGGL(k_nbr_conv1, dim3((npad + 255) / 256), dim3(256), 0, stream,
                     slin, featss, w1, grid, nbr, x1bf, n, npad);
  const int waves = npad / 32;
  const int cblocks = (waves + 3) / 4;
  hipLaunchKernelGGL(k_conv2r, dim3(cblocks), dim3(256), 0, stream,
                     nbr, x1bf, w2pk, x2bf, n, npad);
  hipLaunchKernelGGL(k_conv3r, dim3(cblocks), dim3(256), 0, stream,
                     nbr, x2bf, w3pk, wm, bm, outf, sof, n, npad);
}

// Round 9
// 110.397 us; speedup vs baseline: 1.2985x; 1.0674x over previous
//
#include <hip/hip_runtime.h>

#define GD 128
#define GD3 (GD*GD*GD)
#define CPB 2048
#define NSCAN (GD3 / CPB)
// nbr16: group-major int16 delta rulebook, [g][28 planes][32 slots] shorts.
// Entry for sorted row i (g=i>>5, slot=(i&15)*2+((i>>4)&1)) at g*896 + k*32 + slot.
// Value: rank delta (idx - i), or 0x8000 sentinel (inactive). Plane 27 = sentinel pad
// (conv2's pair (26,27)).

typedef __attribute__((ext_vector_type(8))) __bf16 bf16x8;
typedef __attribute__((ext_vector_type(4))) float f32x4;
typedef __attribute__((ext_vector_type(4))) unsigned int u32x4;

#define SB() __builtin_amdgcn_sched_barrier(0)

__device__ __forceinline__ unsigned short f2bf(float x) {
  unsigned int u = __builtin_bit_cast(unsigned int, x);
  unsigned int r = (u + 0x7FFFu + ((u >> 16) & 1u)) >> 16;  // RNE
  return (unsigned short)r;
}

// Bijective XCD-chunked block swizzle (m204).
__device__ __forceinline__ int xcd_swz(int bid, int nwg) {
  int q = nwg >> 3, r = nwg & 7;
  int x = bid & 7, inner = bid >> 3;
  int base = (x < r) ? x * (q + 1) : r * (q + 1) + (x - r) * q;
  return base + inner;
}

__global__ void k_init_grid(int* __restrict__ g) {
  int i = (blockIdx.x * 256 + threadIdx.x) * 4;
  if (i < GD3) *(u32x4*)(g + i) = (u32x4){0xFFFFFFFFu,0xFFFFFFFFu,0xFFFFFFFFu,0xFFFFFFFFu};
}

__global__ void k_scatter(const int* __restrict__ coords, int* __restrict__ g, int n) {
  int i = blockIdx.x * 256 + threadIdx.x;
  if (i >= n) return;
  int x = coords[3*i], y = coords[3*i+1], z = coords[3*i+2];
  g[(x << 14) | (y << 7) | z] = i;
}

__global__ void k_count(const int* __restrict__ g, int* __restrict__ bcnt) {
  __shared__ int wtot[4];
  int t = threadIdx.x, lane = t & 63, w = t >> 6;
  const int* c = g + blockIdx.x * CPB + t * 8;
  int cnt = 0;
  #pragma unroll
  for (int j = 0; j < 8; j++) cnt += (c[j] >= 0) ? 1 : 0;
  #pragma unroll
  for (int d = 1; d < 64; d <<= 1) cnt += __shfl_xor(cnt, d);
  if (lane == 0) wtot[w] = cnt;
  __syncthreads();
  if (t == 0) bcnt[blockIdx.x] = wtot[0] + wtot[1] + wtot[2] + wtot[3];
}

__global__ void k_scan(const int* __restrict__ bcnt, int* __restrict__ boff) {
  __shared__ int s[NSCAN];
  int t = threadIdx.x;
  int v = bcnt[t];
  s[t] = v;
  __syncthreads();
  #pragma unroll
  for (int d = 1; d < NSCAN; d <<= 1) {
    int y = (t >= d) ? s[t - d] : 0;
    __syncthreads();
    s[t] += y;
    __syncthreads();
  }
  boff[t] = s[t] - v;
}

// Compact in-place: grid cell -> sorted rank (-1 if empty); emit sof/slin/featss.
__global__ void k_compact(int* __restrict__ g, const float* __restrict__ feats,
                          const int* __restrict__ boff,
                          int* __restrict__ sof, int* __restrict__ slin,
                          float* __restrict__ featss) {
  __shared__ int wtot[4];
  int t = threadIdx.x, lane = t & 63, w = t >> 6;
  int cbase = blockIdx.x * CPB + t * 8;
  int v[8]; int cnt = 0;
  #pragma unroll
  for (int j = 0; j < 8; j++) { v[j] = g[cbase + j]; cnt += (v[j] >= 0) ? 1 : 0; }
  int x = cnt;
  #pragma unroll
  for (int d = 1; d < 64; d <<= 1) { int y = __shfl_up(x, d); if (lane >= d) x += y; }
  if (lane == 63) wtot[w] = x;
  __syncthreads();
  int wbase = 0;
  for (int ww = 0; ww < w; ww++) wbase += wtot[ww];
  int pos = boff[blockIdx.x] + wbase + (x - cnt);
  #pragma unroll
  for (int j = 0; j < 8; j++) {
    int o = v[j];
    if (o >= 0) {
      g[cbase + j] = pos;
      sof[pos] = o;
      slin[pos] = cbase + j;
      featss[pos] = feats[o];
      pos++;
    } else {
      g[cbase + j] = -1;
    }
  }
}

// Pack weights into MFMA B-fragment order, bf16 (same as round 8, passed).
__global__ void k_wpack(const float* __restrict__ w2, const float* __restrict__ w3,
                        unsigned short* __restrict__ w2pk, unsigned short* __restrict__ w3pk,
                        unsigned short* __restrict__ x1bf, unsigned short* __restrict__ x2bf,
                        int n) {
  int gid = blockIdx.x * 256 + threadIdx.x;
  const int N3 = 29 * 4 * 64;   // 7424
  const int N2 = 16 * 2 * 64;   // 2048
  if (gid < N3) {
    int k = gid >> 8, rem = gid & 255, c = rem >> 6, l = rem & 63;
    int gq = l >> 4, col = l & 15;
    #pragma unroll
    for (int j = 0; j < 8; j++) {
      int ci = gq * 8 + j, co = c * 16 + col;
      float v = (k < 27) ? w3[(k * 32 + ci) * 64 + co] : 0.f;
      w3pk[gid * 8 + j] = f2bf(v);
    }
  } else if (gid < N3 + N2) {
    int g2 = gid - N3;
    int s = g2 >> 7, rem = g2 & 127, c = rem >> 6, l = rem & 63;
    int gq = l >> 4, col = l & 15;
    int k = 2 * s + (gq >> 1);
    #pragma unroll
    for (int j = 0; j < 8; j++) {
      int ci = (gq & 1) * 8 + j, co = c * 16 + col;
      float v = (k < 27) ? w2[(k * 16 + ci) * 32 + co] : 0.f;
      w2pk[g2 * 8 + j] = f2bf(v);
    }
  } else if (gid == N3 + N2) {
    u32x4 z = {0u,0u,0u,0u};
    u32x4* d = (u32x4*)(x1bf + (size_t)n * 16);
    d[0] = z; d[1] = z;
  } else if (gid == N3 + N2 + 1) {
    u32x4 z = {0u,0u,0u,0u};
    u32x4* d = (u32x4*)(x2bf + (size_t)n * 32);
    d[0] = z; d[1] = z; d[2] = z; d[3] = z;
  }
}

// Rulebook (int16 deltas, group-major) fused with conv1 (1->16 ch).
__global__ void k_nbr_conv1(const int* __restrict__ slin, const float* __restrict__ featss,
                            const float* __restrict__ w1, const int* __restrict__ g2,
                            short* __restrict__ nbr16, unsigned short* __restrict__ x1bf,
                            int n, int npad) {
  int bid = xcd_swz(blockIdx.x, gridDim.x);
  int i = bid * 256 + threadIdx.x;
  if (i >= npad) return;
  short* nb = nbr16 + (size_t)(i >> 5) * 896 + ((i & 15) << 1) + ((i >> 4) & 1);
  if (i >= n) {
    #pragma unroll
    for (int k = 0; k < 28; k++) nb[k * 32] = (short)0x8000;
    return;
  }
  int lin = slin[i];
  int x = lin >> 14, y = (lin >> 7) & 127, z = lin & 127;
  // Phase 1: all 27 grid lookups, branchless, issued together.
  int idxs[27];
  #pragma unroll
  for (int k = 0; k < 27; k++) {
    const int dx = k/9 - 1, dy = (k/3)%3 - 1, dz = k%3 - 1;
    int nx = x+dx, ny = y+dy, nz = z+dz;
    bool valid = ((unsigned)nx < 128u) && ((unsigned)ny < 128u) && ((unsigned)nz < 128u);
    int nlin = valid ? ((nx << 14) | (ny << 7) | nz) : 0;
    int v = g2[nlin];
    idxs[k] = valid ? v : -1;
  }
  SB();
  // Phase 2: delta rulebook writes + feature gathers.
  float fv[27];
  #pragma unroll
  for (int k = 0; k < 27; k++) {
    int idx = idxs[k];
    nb[k * 32] = (idx >= 0) ? (short)(idx - i) : (short)0x8000;
    float f = featss[(idx >= 0) ? idx : 0];
    fv[k] = (idx >= 0) ? f : 0.f;
  }
  nb[27 * 32] = (short)0x8000;
  SB();
  // Phase 3: conv1 FMAs.
  float acc[16];
  #pragma unroll
  for (int c = 0; c < 16; c++) acc[c] = 0.f;
  #pragma unroll
  for (int k = 0; k < 27; k++)
    #pragma unroll
    for (int c = 0; c < 16; c++) acc[c] = fmaf(fv[k], w1[k*16+c], acc[c]);
  u32x4 d0, d1;
  d0.x = (unsigned)f2bf(acc[0])  | ((unsigned)f2bf(acc[1])  << 16);
  d0.y = (unsigned)f2bf(acc[2])  | ((unsigned)f2bf(acc[3])  << 16);
  d0.z = (unsigned)f2bf(acc[4])  | ((unsigned)f2bf(acc[5])  << 16);
  d0.w = (unsigned)f2bf(acc[6])  | ((unsigned)f2bf(acc[7])  << 16);
  d1.x = (unsigned)f2bf(acc[8])  | ((unsigned)f2bf(acc[9])  << 16);
  d1.y = (unsigned)f2bf(acc[10]) | ((unsigned)f2bf(acc[11]) << 16);
  d1.z = (unsigned)f2bf(acc[12]) | ((unsigned)f2bf(acc[13]) << 16);
  d1.w = (unsigned)f2bf(acc[14]) | ((unsigned)f2bf(acc[15]) << 16);
  u32x4* dst = (u32x4*)(x1bf + (size_t)i * 16);
  dst[0] = d0; dst[1] = d1;
}

// Decode one packed delta dword -> two row indices (sentinel -> n = zero row).
__device__ __forceinline__ void dec2(int d, int i0, int i1, int n, int& ix, int& iy) {
  int s0 = (int)(short)(d & 0xffff);
  int s1 = d >> 16;
  ix = (s0 == -32768) ? n : i0 + s0;
  iy = (s1 == -32768) ? n : i1 + s1;
}

// conv2, k-PAIRED (14 steps). ALL idx dwords preloaded + use-fenced; loop is warm-only.
__launch_bounds__(256, 3)
__global__ void k_conv2r(const short* __restrict__ nbr16, const unsigned short* __restrict__ xin,
                         const unsigned short* __restrict__ wpk,
                         unsigned short* __restrict__ xout, int n, int npad) {
  const int lane = threadIdx.x & 63;
  const int w = threadIdx.x >> 6;
  const int bid = xcd_swz(blockIdx.x, gridDim.x);
  const int base = (bid * 4 + w) * 32;
  if (base >= npad) return;
  const int col = lane & 15, grp = lane >> 4;
  const int kg = grp >> 1;
  const int* nbd = (const int*)(nbr16 + (size_t)(base >> 5) * 896) + col;  // plane p at +p*16
  const unsigned short* xg = xin + (grp & 1) * 8;
  const unsigned short* wl = wpk + lane * 8;
  const int i0 = base + col, i1 = base + 16 + col;

  // Preload ALL 14 idx dwords (this lane's plane = 2s+kg), then force completion.
  int idxd[14];
  #pragma unroll
  for (int s = 0; s < 14; s++) idxd[s] = nbd[(2 * s + kg) * 16];
  // B prologue issued before the idx fence so it overlaps the L3 round-trip.
  bf16x8 bst[3][2];
  #pragma unroll
  for (int c = 0; c < 2; c++) bst[0][c] = *(const bf16x8*)(wl + (size_t)(0*2+c)*512);
  #pragma unroll
  for (int c = 0; c < 2; c++) bst[1][c] = *(const bf16x8*)(wl + (size_t)(1*2+c)*512);
  int pin = 0;
  #pragma unroll
  for (int s = 0; s < 14; s++) pin += idxd[s];
  asm volatile("" :: "v"(pin));   // forces all idx loads complete pre-loop; not sinkable
  SB();
  bf16x8 ga[4][2];
  #pragma unroll
  for (int s = 0; s < 3; s++) {
    int ix, iy; dec2(idxd[s], i0, i1, n, ix, iy);
    ga[s][0] = *(const bf16x8*)(xg + (size_t)ix * 16);
    ga[s][1] = *(const bf16x8*)(xg + (size_t)iy * 16);
  }
  SB();

  f32x4 acc[2][2];
  #pragma unroll
  for (int t = 0; t < 2; t++)
    #pragma unroll
    for (int c = 0; c < 2; c++) acc[t][c] = (f32x4){0.f,0.f,0.f,0.f};

  #pragma unroll
  for (int s = 0; s < 14; ++s) {
    SB();
    #pragma unroll
    for (int c = 0; c < 2; c++) {
      acc[0][c] = __builtin_amdgcn_mfma_f32_16x16x32_bf16(ga[s%4][0], bst[s%3][c], acc[0][c], 0, 0, 0);
      acc[1][c] = __builtin_amdgcn_mfma_f32_16x16x32_bf16(ga[s%4][1], bst[s%3][c], acc[1][c], 0, 0, 0);
    }
    SB();
    if (s + 2 < 14) {
      #pragma unroll
      for (int c = 0; c < 2; c++)
        bst[(s+2)%3][c] = *(const bf16x8*)(wl + (size_t)((s+2)*2+c)*512);
    }
    if (s + 3 < 14) {
      int ix, iy; dec2(idxd[s+3], i0, i1, n, ix, iy);
      ga[(s+3)%4][0] = *(const bf16x8*)(xg + (size_t)ix * 16);
      ga[(s+3)%4][1] = *(const bf16x8*)(xg + (size_t)iy * 16);
    }
  }

  #pragma unroll
  for (int t = 0; t < 2; t++)
    #pragma unroll
    for (int c = 0; c < 2; c++)
      #pragma unroll
      for (int r = 0; r < 4; r++) {
        int m = base + t*16 + grp*4 + r;
        if (m < n) xout[(size_t)m * 32 + c*16 + col] = f2bf(acc[t][c][r]);
      }
}

// conv3 (27 planes, 4 chunks). ALL idx preloaded + fenced; warm-only loop; fused head.
__launch_bounds__(256, 3)
__global__ void k_conv3r(const short* __restrict__ nbr16, const unsigned short* __restrict__ xin,
                         const unsigned short* __restrict__ wpk,
                         const float* __restrict__ wm, const float* __restrict__ bm,
                         float* __restrict__ outf, const int* __restrict__ sof,
                         int n, int npad) {
  const int lane = threadIdx.x & 63;
  const int w = threadIdx.x >> 6;
  const int bid = xcd_swz(blockIdx.x, gridDim.x);
  const int base = (bid * 4 + w) * 32;
  if (base >= npad) return;
  const int col = lane & 15, grp = lane >> 4;
  const int* nbd = (const int*)(nbr16 + (size_t)(base >> 5) * 896) + col;
  const unsigned short* xg = xin + grp * 8;      // + idx*32
  const unsigned short* wl = wpk + lane * 8;     // plane k chunk c at + (k*4+c)*512
  const int i0 = base + col, i1 = base + 16 + col;

  int idxd[27];
  #pragma unroll
  for (int k = 0; k < 27; k++) idxd[k] = nbd[k * 16];
  bf16x8 bst[3][4];
  #pragma unroll
  for (int c = 0; c < 4; c++) bst[0][c] = *(const bf16x8*)(wl + (size_t)(0*4+c)*512);
  #pragma unroll
  for (int c = 0; c < 4; c++) bst[1][c] = *(const bf16x8*)(wl + (size_t)(1*4+c)*512);
  int pin = 0;
  #pragma unroll
  for (int k = 0; k < 27; k++) pin += idxd[k];
  asm volatile("" :: "v"(pin));
  SB();
  bf16x8 ga[4][2];
  #pragma unroll
  for (int k = 0; k < 3; k++) {
    int ix, iy; dec2(idxd[k], i0, i1, n, ix, iy);
    ga[k][0] = *(const bf16x8*)(xg + (size_t)ix * 32);
    ga[k][1] = *(const bf16x8*)(xg + (size_t)iy * 32);
  }
  SB();

  f32x4 acc[2][4];
  #pragma unroll
  for (int t = 0; t < 2; t++)
    #pragma unroll
    for (int c = 0; c < 4; c++) acc[t][c] = (f32x4){0.f,0.f,0.f,0.f};

  #pragma unroll
  for (int k = 0; k < 27; ++k) {
    SB();
    #pragma unroll
    for (int c = 0; c < 4; c++) {
      acc[0][c] = __builtin_amdgcn_mfma_f32_16x16x32_bf16(ga[k%4][0], bst[k%3][c], acc[0][c], 0, 0, 0);
      acc[1][c] = __builtin_amdgcn_mfma_f32_16x16x32_bf16(ga[k%4][1], bst[k%3][c], acc[1][c], 0, 0, 0);
    }
    SB();
    if (k + 2 < 27) {
      #pragma unroll
      for (int c = 0; c < 4; c++)
        bst[(k+2)%3][c] = *(const bf16x8*)(wl + (size_t)((k+2)*4+c)*512);
    }
    if (k + 3 < 27) {
      int ix, iy; dec2(idxd[k+3], i0, i1, n, ix, iy);
      ga[(k+3)%4][0] = *(const bf16x8*)(xg + (size_t)ix * 32);
      ga[(k+3)%4][1] = *(const bf16x8*)(xg + (size_t)iy * 32);
    }
  }

  float wmv[4][3];
  #pragma unroll
  for (int c = 0; c < 4; c++)
    #pragma unroll
    for (int j = 0; j < 3; j++) wmv[c][j] = wm[(c*16 + col)*3 + j];
  float bb0 = bm[0], bb1 = bm[1], bb2 = bm[2];
  #pragma unroll
  for (int t = 0; t < 2; t++)
    #pragma unroll
    for (int r = 0; r < 4; r++) {
      float p0 = 0.f, p1 = 0.f, p2 = 0.f;
      #pragma unroll
      for (int c = 0; c < 4; c++) {
        float v = acc[t][c][r];
        p0 = fmaf(v, wmv[c][0], p0);
        p1 = fmaf(v, wmv[c][1], p1);
        p2 = fmaf(v, wmv[c][2], p2);
      }
      #pragma unroll
      for (int msk = 1; msk <= 8; msk <<= 1) {
        p0 += __shfl_xor(p0, msk);
        p1 += __shfl_xor(p1, msk);
        p2 += __shfl_xor(p2, msk);
      }
      if (col == 0) {
        int m = base + t*16 + grp*4 + r;
        if (m < n) {
          int o = sof[m];
          outf[o*3+0] = p0 + bb0;
          outf[o*3+1] = p1 + bb1;
          outf[o*3+2] = p2 + bb2;
        }
      }
    }
}

extern "C" void kernel_launch(void* const* d_in, const int* in_sizes, int n_in,
                              void* d_out, int out_size, void* d_ws, size_t ws_size,
                              hipStream_t stream) {
  (void)n_in; (void)out_size; (void)ws_size;
  const int*   coords = (const int*)d_in[0];
  const float* feats  = (const float*)d_in[1];
  const float* w1     = (const float*)d_in[2];
  const float* w2     = (const float*)d_in[3];
  const float* w3     = (const float*)d_in[4];
  const float* wm     = (const float*)d_in[5];
  const float* bm     = (const float*)d_in[6];
  float* outf = (float*)d_out;
  const int n = in_sizes[0] / 3;
  const int npad = (n + 31) & ~31;

  char* ws = (char*)d_ws;
  size_t off = 0;
  int* grid = (int*)(ws + off); off += (size_t)GD3 * 4;
  short* nbr16 = (short*)(ws + off); off += (size_t)(npad / 32) * 896 * 2;
  off = (off + 255) & ~(size_t)255;
  int* bcnt = (int*)(ws + off); off += (size_t)NSCAN * 4;
  int* boff = (int*)(ws + off); off += (size_t)NSCAN * 4;
  off = (off + 255) & ~(size_t)255;
  int* sof  = (int*)(ws + off); off += (size_t)npad * 4;
  int* slin = (int*)(ws + off); off += (size_t)npad * 4;
  float* featss = (float*)(ws + off); off += (size_t)npad * 4;
  off = (off + 255) & ~(size_t)255;
  unsigned short* x1bf = (unsigned short*)(ws + off); off += ((size_t)n + 1) * 16 * 2;
  off = (off + 255) & ~(size_t)255;
  unsigned short* x2bf = (unsigned short*)(ws + off); off += ((size_t)n + 1) * 32 * 2;
  off = (off + 255) & ~(size_t)255;
  unsigned short* w2pk = (unsigned short*)(ws + off); off += (size_t)16 * 2 * 64 * 8 * 2;
  off = (off + 255) & ~(size_t)255;
  unsigned short* w3pk = (unsigned short*)(ws + off); off += (size_t)29 * 4 * 64 * 8 * 2;

  hipLaunchKernelGGL(k_init_grid, dim3(GD3 / 1024), dim3(256), 0, stream, grid);
  hipLaunchKernelGGL(k_scatter, dim3((n + 255) / 256), dim3(256), 0, stream, coords, grid, n);
  hipLaunchKernelGGL(k_count, dim3(NSCAN), dim3(256), 0, stream, grid, bcnt);
  hipLaunchKernelGGL(k_scan, dim3(1), dim3(NSCAN), 0, stream, bcnt, boff);
  hipLaunchKernelGGL(k_compact, dim3(NSCAN), dim3(256), 0, stream,
                     grid, feats, boff, sof, slin, featss);
  {
    const int items = 29*4*64 + 16*2*64 + 2;
    hipLaunchKernelGGL(k_wpack, dim3((items + 255) / 256), dim3(256), 0, stream,
                       w2, w3, w2pk, w3pk, x1bf, x2bf, n);
  }
  hipLaunchKernelGGL(k_nbr_conv1, dim3((npad + 255) / 256), dim3(256), 0, stream,
                     slin, featss, w1, grid, nbr16, x1bf, n, npad);
  const int waves = npad / 32;
  const int cblocks = (waves + 3) / 4;
  hipLaunchKernelGGL(k_conv2r, dim3(cblocks), dim3(256), 0, stream,
                     nbr16, x1bf, w2pk, x2bf, n, npad);
  hipLaunchKernelGGL(k_conv3r, dim3(cblocks), dim3(256), 0, stream,
                     nbr16, x2bf, w3pk, wm, bm, outf, sof, n, npad);
}